// Round 3
// baseline (942.922 us; speedup 1.0000x reference)
//
#include <hip/hip_runtime.h>
#include <hip/hip_bf16.h>
#include <math.h>

#define N_NODES_C 100000
#define N_EDGES_C 1600000
#define N_GRAPHS_C 512
#define SCAN_CHUNK 1024   // elements per scan block
#define SCAN_NB ((N_NODES_C + SCAN_CHUNK) / SCAN_CHUNK + 1)  // generous

__device__ __forceinline__ float elu_f(float x) { return x > 0.f ? x : expm1f(x); }

__device__ __forceinline__ int wave_incl_scan(int v) {
    int lane = threadIdx.x & 63;
#pragma unroll
    for (int o = 1; o < 64; o <<= 1) {
        int t = __shfl_up(v, o);
        if (lane >= o) v += t;
    }
    return v;
}

__device__ __forceinline__ int wave_sum_i(int v) {
#pragma unroll
    for (int o = 32; o > 0; o >>= 1) v += __shfl_xor(v, o);
    return v;
}

// ---------------------------------------------------------------------------
// CSR build: histogram of in-degrees, exclusive scan, positioned fill.
// ---------------------------------------------------------------------------
__global__ __launch_bounds__(256) void hist_kernel(
    const int* __restrict__ dst, int* __restrict__ deg, int nE)
{
    int e = blockIdx.x * 256 + threadIdx.x;
    if (e < nE) atomicAdd(&deg[dst[e]], 1);
}

__global__ __launch_bounds__(256) void scan_pass1(
    const int* __restrict__ deg, int* __restrict__ bsum, int n)
{
    int base = blockIdx.x * SCAN_CHUNK;
    int s = 0;
    for (int i = threadIdx.x; i < SCAN_CHUNK; i += 256) {
        int idx = base + i;
        if (idx < n) s += deg[idx];
    }
    s = wave_sum_i(s);
    __shared__ int ws[4];
    int lane = threadIdx.x & 63, w = threadIdx.x >> 6;
    if (lane == 0) ws[w] = s;
    __syncthreads();
    if (threadIdx.x == 0) bsum[blockIdx.x] = ws[0] + ws[1] + ws[2] + ws[3];
}

__global__ __launch_bounds__(128) void scan_pass2(int* __restrict__ bsum, int nb)
{
    int tid = threadIdx.x;  // 128 threads, nb <= 128
    int v = tid < nb ? bsum[tid] : 0;
    int lane = tid & 63, w = tid >> 6;
    int incl = wave_incl_scan(v);
    __shared__ int ws[2];
    if (lane == 63) ws[w] = incl;
    __syncthreads();
    int off = (w == 1) ? ws[0] : 0;
    if (tid < nb) bsum[tid] = off + incl - v;  // exclusive
}

__global__ __launch_bounds__(256) void scan_pass3(
    const int* __restrict__ deg, const int* __restrict__ bsum,
    int* __restrict__ row_start, int* __restrict__ pos, int n)
{
    int base = blockIdx.x * SCAN_CHUNK + threadIdx.x * 4;
    int v[4];
#pragma unroll
    for (int k = 0; k < 4; ++k) {
        int idx = base + k;
        v[k] = (idx < n) ? deg[idx] : 0;
    }
    int lsum = v[0] + v[1] + v[2] + v[3];
    int incl = wave_incl_scan(lsum);
    __shared__ int ws[4];
    int lane = threadIdx.x & 63, w = threadIdx.x >> 6;
    if (lane == 63) ws[w] = incl;
    __syncthreads();
    int woff = 0;
    for (int i = 0; i < w; ++i) woff += ws[i];
    int p = bsum[blockIdx.x] + woff + incl - lsum;  // exclusive base
#pragma unroll
    for (int k = 0; k < 4; ++k) {
        int idx = base + k;
        if (idx <= n) row_start[idx] = p;
        if (idx < n)  pos[idx] = p;
        p += v[k];
    }
}

__global__ __launch_bounds__(256) void fill_kernel(
    const int* __restrict__ src, const int* __restrict__ dst,
    int* __restrict__ pos, int* __restrict__ ssrc, int nE)
{
    int e = blockIdx.x * 256 + threadIdx.x;
    if (e < nE) {
        int p = atomicAdd(&pos[dst[e]], 1);
        ssrc[p] = src[e];
    }
}

// ---------------------------------------------------------------------------
// Gather-sum aggregation: agg[n] = sum_{e in CSR[n]} x[ssrc[e]].
// D/4 lanes per node, float4 per lane, register accumulation, no atomics.
// ---------------------------------------------------------------------------
template<int D>
__global__ __launch_bounds__(256) void gather_agg(
    const float* __restrict__ x, const int* __restrict__ row_start,
    const int* __restrict__ ssrc, float* __restrict__ agg, int nNodes)
{
    const int L = D / 4;        // lanes per node
    const int NPB = 256 / L;    // nodes per block
    int local = threadIdx.x / L;
    int lane  = threadIdx.x % L;
    int n = blockIdx.x * NPB + local;
    if (n >= nNodes) return;
    int beg = row_start[n], end = row_start[n + 1];
    float4 acc = make_float4(0.f, 0.f, 0.f, 0.f);
    int e = beg;
    for (; e + 1 < end; e += 2) {
        int s0 = ssrc[e], s1 = ssrc[e + 1];
        float4 v0 = *reinterpret_cast<const float4*>(x + (size_t)s0 * D + lane * 4);
        float4 v1 = *reinterpret_cast<const float4*>(x + (size_t)s1 * D + lane * 4);
        acc.x += v0.x; acc.y += v0.y; acc.z += v0.z; acc.w += v0.w;
        acc.x += v1.x; acc.y += v1.y; acc.z += v1.z; acc.w += v1.w;
    }
    if (e < end) {
        int s0 = ssrc[e];
        float4 v0 = *reinterpret_cast<const float4*>(x + (size_t)s0 * D + lane * 4);
        acc.x += v0.x; acc.y += v0.y; acc.z += v0.z; acc.w += v0.w;
    }
    *reinterpret_cast<float4*>(agg + (size_t)n * D + lane * 4) = acc;
}

// ---------------------------------------------------------------------------
// Node transform v2 (register-blocked):
//   thread = (node, j-quad). Input rows via float4 (broadcast within wave),
//   weights via ds_read_b128, 4 accumulators in VGPRs, fully unrolled.
// out[n][j0..j0+3] = ELU( agg[n]@w_rel + x[n]@w_root + b )[j0..j0+3]
// ---------------------------------------------------------------------------
template<int DIN, int DOUT>
__global__ __launch_bounds__(256) void transform_v2(
    const float* __restrict__ agg, const float* __restrict__ xin,
    const float* __restrict__ w_rel, const float* __restrict__ bias,
    const float* __restrict__ w_root, float* __restrict__ out, int nNodes)
{
    const int TPN = DOUT / 4;   // threads per node
    const int NPB = 256 / TPN;  // nodes per block
    __shared__ float wr[DIN * DOUT];
    __shared__ float wt[DIN * DOUT];
    for (int i = threadIdx.x; i < DIN * DOUT; i += 256) {
        wr[i] = w_rel[i];
        wt[i] = w_root[i];
    }
    __syncthreads();

    int local = threadIdx.x / TPN;
    int j0 = (threadIdx.x % TPN) * 4;
    int n = blockIdx.x * NPB + local;
    if (n >= nNodes) return;

    const float4* ar = reinterpret_cast<const float4*>(agg + (size_t)n * DIN);
    const float4* xr = reinterpret_cast<const float4*>(xin + (size_t)n * DIN);
    float4 acc = *reinterpret_cast<const float4*>(bias + j0);

#pragma unroll
    for (int c = 0; c < DIN / 4; ++c) {
        float4 a4 = ar[c];
        float4 x4 = xr[c];
#pragma unroll
        for (int kk = 0; kk < 4; ++kk) {
            int k = c * 4 + kk;
            float av = kk == 0 ? a4.x : kk == 1 ? a4.y : kk == 2 ? a4.z : a4.w;
            float xv = kk == 0 ? x4.x : kk == 1 ? x4.y : kk == 2 ? x4.z : x4.w;
            float4 w4 = *reinterpret_cast<const float4*>(&wr[k * DOUT + j0]);
            float4 t4 = *reinterpret_cast<const float4*>(&wt[k * DOUT + j0]);
            acc.x += av * w4.x + xv * t4.x;
            acc.y += av * w4.y + xv * t4.y;
            acc.z += av * w4.z + xv * t4.z;
            acc.w += av * w4.w + xv * t4.w;
        }
    }
    float4 o;
    o.x = elu_f(acc.x);
    o.y = elu_f(acc.y);
    o.z = elu_f(acc.z);
    o.w = elu_f(acc.w);
    *reinterpret_cast<float4*>(out + (size_t)n * DOUT + j0) = o;
}

// ---------------------------------------------------------------------------
// Mean-pool over sorted `batch`.
// ---------------------------------------------------------------------------
#define POOL_CHUNK 256
__global__ __launch_bounds__(64) void pool_kernel(
    const float* __restrict__ h, const int* __restrict__ batch,
    float* __restrict__ sums, float* __restrict__ cnts, int nNodes)
{
    int j = threadIdx.x;
    int start = blockIdx.x * POOL_CHUNK;
    int end = start + POOL_CHUNK;
    if (end > nNodes) end = nNodes;
    if (start >= end) return;

    int g = batch[start];
    float acc = 0.f;
    float c = 0.f;
    for (int n = start; n < end; ++n) {
        int gn = batch[n];
        if (gn != g) {
            unsafeAtomicAdd(&sums[(size_t)g * 64 + j], acc);
            if (j == 0) unsafeAtomicAdd(&cnts[g], c);
            acc = 0.f; c = 0.f; g = gn;
        }
        acc += h[(size_t)n * 64 + j];
        c += 1.f;
    }
    unsafeAtomicAdd(&sums[(size_t)g * 64 + j], acc);
    if (j == 0) unsafeAtomicAdd(&cnts[g], c);
}

// ---------------------------------------------------------------------------
// MLP head + log_softmax: one 64-thread block per graph.
// ---------------------------------------------------------------------------
__global__ __launch_bounds__(64) void mlp_kernel(
    const float* __restrict__ sums, const float* __restrict__ cnts,
    const float* __restrict__ fw1, const float* __restrict__ fb1,
    const float* __restrict__ fw2, const float* __restrict__ fb2,
    const float* __restrict__ fw3, const float* __restrict__ fb3,
    float* __restrict__ out)
{
    int g = blockIdx.x;
    int j = threadIdx.x;
    __shared__ float p[64];
    __shared__ float z1[64];
    __shared__ float z2[32];
    __shared__ float z3[10];
    __shared__ float lse;

    float c = fmaxf(cnts[g], 1.f);
    p[j] = sums[(size_t)g * 64 + j] / c;
    __syncthreads();

    float a = fb1[j];
#pragma unroll
    for (int k = 0; k < 64; ++k) a += p[k] * fw1[k * 64 + j];
    z1[j] = elu_f(a);
    __syncthreads();

    if (j < 32) {
        float a2 = fb2[j];
#pragma unroll
        for (int k = 0; k < 64; ++k) a2 += z1[k] * fw2[k * 32 + j];
        z2[j] = elu_f(a2);
    }
    __syncthreads();

    if (j < 10) {
        float a3 = fb3[j];
#pragma unroll
        for (int k = 0; k < 32; ++k) a3 += z2[k] * fw3[k * 10 + j];
        z3[j] = a3;
    }
    __syncthreads();

    if (j == 0) {
        float m = -1e30f;
        for (int i = 0; i < 10; ++i) m = fmaxf(m, z3[i]);
        float s = 0.f;
        for (int i = 0; i < 10; ++i) s += expf(z3[i] - m);
        lse = logf(s) + m;
    }
    __syncthreads();

    if (j < 10) out[(size_t)g * 10 + j] = z3[j] - lse;
}

// ---------------------------------------------------------------------------
extern "C" void kernel_launch(void* const* d_in, const int* in_sizes, int n_in,
                              void* d_out, int out_size, void* d_ws, size_t ws_size,
                              hipStream_t stream)
{
    const float* x       = (const float*)d_in[0];
    const int*   ei      = (const int*)  d_in[1];
    const int*   batch   = (const int*)  d_in[2];
    const float* w1_rel  = (const float*)d_in[3];
    const float* b1      = (const float*)d_in[4];
    const float* w1_root = (const float*)d_in[5];
    const float* w2_rel  = (const float*)d_in[6];
    const float* b2      = (const float*)d_in[7];
    const float* w2_root = (const float*)d_in[8];
    const float* w3_rel  = (const float*)d_in[9];
    const float* b3      = (const float*)d_in[10];
    const float* w3_root = (const float*)d_in[11];
    const float* fw1     = (const float*)d_in[12];
    const float* fb1     = (const float*)d_in[13];
    const float* fw2     = (const float*)d_in[14];
    const float* fb2     = (const float*)d_in[15];
    const float* fw3     = (const float*)d_in[16];
    const float* fb3     = (const float*)d_in[17];
    float* out = (float*)d_out;

    const int* src = ei;
    const int* dst = ei + N_EDGES_C;

    // workspace layout
    float* agg  = (float*)d_ws;                          // N*64 f
    float* hB   = agg  + (size_t)N_NODES_C * 64;         // N*64 f
    float* hC   = hB   + (size_t)N_NODES_C * 64;         // N*64 f
    float* sums = hC   + (size_t)N_NODES_C * 64;         // 512*64 f
    float* cnts = sums + (size_t)N_GRAPHS_C * 64;        // 512 f
    int*   deg  = (int*)(cnts + N_GRAPHS_C);             // N int
    int*   row_start = deg + N_NODES_C;                  // N+1 int
    int*   pos  = row_start + N_NODES_C + 1;             // N int
    int*   bsum = pos + N_NODES_C;                       // SCAN_NB int
    int*   ssrc = bsum + SCAN_NB;                        // nE int

    const int nb = (N_NODES_C + SCAN_CHUNK - 1) / SCAN_CHUNK;  // 98

    // ---- CSR build (once, reused by all 3 layers) ----
    hipMemsetAsync(deg, 0, (size_t)N_NODES_C * sizeof(int), stream);
    hist_kernel<<<(N_EDGES_C + 255) / 256, 256, 0, stream>>>(dst, deg, N_EDGES_C);
    scan_pass1<<<nb, 256, 0, stream>>>(deg, bsum, N_NODES_C);
    scan_pass2<<<1, 128, 0, stream>>>(bsum, nb);
    scan_pass3<<<nb, 256, 0, stream>>>(deg, bsum, row_start, pos, N_NODES_C);
    fill_kernel<<<(N_EDGES_C + 255) / 256, 256, 0, stream>>>(src, dst, pos, ssrc, N_EDGES_C);

    // ---- layer 1: 32 -> 32, input x, output hB ----
    gather_agg<32><<<(N_NODES_C + 31) / 32, 256, 0, stream>>>(x, row_start, ssrc, agg, N_NODES_C);
    transform_v2<32, 32><<<(N_NODES_C + 31) / 32, 256, 0, stream>>>(
        agg, x, w1_rel, b1, w1_root, hB, N_NODES_C);

    // ---- layer 2: 32 -> 64, input hB, output hC ----
    gather_agg<32><<<(N_NODES_C + 31) / 32, 256, 0, stream>>>(hB, row_start, ssrc, agg, N_NODES_C);
    transform_v2<32, 64><<<(N_NODES_C + 15) / 16, 256, 0, stream>>>(
        agg, hB, w2_rel, b2, w2_root, hC, N_NODES_C);

    // ---- layer 3: 64 -> 64, input hC, output hB ----
    gather_agg<64><<<(N_NODES_C + 15) / 16, 256, 0, stream>>>(hC, row_start, ssrc, agg, N_NODES_C);
    transform_v2<64, 64><<<(N_NODES_C + 15) / 16, 256, 0, stream>>>(
        agg, hC, w3_rel, b3, w3_root, hB, N_NODES_C);

    // ---- mean pool ----
    hipMemsetAsync(sums, 0, ((size_t)N_GRAPHS_C * 64 + N_GRAPHS_C) * sizeof(float), stream);
    pool_kernel<<<(N_NODES_C + POOL_CHUNK - 1) / POOL_CHUNK, 64, 0, stream>>>(
        hB, batch, sums, cnts, N_NODES_C);

    // ---- MLP head + log_softmax ----
    mlp_kernel<<<N_GRAPHS_C, 64, 0, stream>>>(
        sums, cnts, fw1, fb1, fw2, fb2, fw3, fb3, out);
}

// Round 4
// 730.574 us; speedup vs baseline: 1.2907x; 1.2907x over previous
//
#include <hip/hip_runtime.h>
#include <hip/hip_bf16.h>
#include <math.h>

#define N_NODES_C 100000
#define N_EDGES_C 1600000
#define N_GRAPHS_C 512
#define SCAN_CHUNK 1024   // elements per scan block
#define SCAN_NB ((N_NODES_C + SCAN_CHUNK) / SCAN_CHUNK + 1)  // generous

__device__ __forceinline__ float elu_f(float x) { return x > 0.f ? x : expm1f(x); }

__device__ __forceinline__ int wave_incl_scan(int v) {
    int lane = threadIdx.x & 63;
#pragma unroll
    for (int o = 1; o < 64; o <<= 1) {
        int t = __shfl_up(v, o);
        if (lane >= o) v += t;
    }
    return v;
}

__device__ __forceinline__ int wave_sum_i(int v) {
#pragma unroll
    for (int o = 32; o > 0; o >>= 1) v += __shfl_xor(v, o);
    return v;
}

// ---------------------------------------------------------------------------
// CSR build: histogram of in-degrees, exclusive scan, positioned fill.
// ---------------------------------------------------------------------------
__global__ __launch_bounds__(256) void hist_kernel(
    const int* __restrict__ dst, int* __restrict__ deg, int nE)
{
    int e = blockIdx.x * 256 + threadIdx.x;
    if (e < nE) atomicAdd(&deg[dst[e]], 1);
}

__global__ __launch_bounds__(256) void scan_pass1(
    const int* __restrict__ deg, int* __restrict__ bsum, int n)
{
    int base = blockIdx.x * SCAN_CHUNK;
    int s = 0;
    for (int i = threadIdx.x; i < SCAN_CHUNK; i += 256) {
        int idx = base + i;
        if (idx < n) s += deg[idx];
    }
    s = wave_sum_i(s);
    __shared__ int ws[4];
    int lane = threadIdx.x & 63, w = threadIdx.x >> 6;
    if (lane == 0) ws[w] = s;
    __syncthreads();
    if (threadIdx.x == 0) bsum[blockIdx.x] = ws[0] + ws[1] + ws[2] + ws[3];
}

__global__ __launch_bounds__(128) void scan_pass2(int* __restrict__ bsum, int nb)
{
    int tid = threadIdx.x;  // 128 threads, nb <= 128
    int v = tid < nb ? bsum[tid] : 0;
    int lane = tid & 63, w = tid >> 6;
    int incl = wave_incl_scan(v);
    __shared__ int ws[2];
    if (lane == 63) ws[w] = incl;
    __syncthreads();
    int off = (w == 1) ? ws[0] : 0;
    if (tid < nb) bsum[tid] = off + incl - v;  // exclusive
}

__global__ __launch_bounds__(256) void scan_pass3(
    const int* __restrict__ deg, const int* __restrict__ bsum,
    int* __restrict__ row_start, int* __restrict__ pos, int n)
{
    int base = blockIdx.x * SCAN_CHUNK + threadIdx.x * 4;
    int v[4];
#pragma unroll
    for (int k = 0; k < 4; ++k) {
        int idx = base + k;
        v[k] = (idx < n) ? deg[idx] : 0;
    }
    int lsum = v[0] + v[1] + v[2] + v[3];
    int incl = wave_incl_scan(lsum);
    __shared__ int ws[4];
    int lane = threadIdx.x & 63, w = threadIdx.x >> 6;
    if (lane == 63) ws[w] = incl;
    __syncthreads();
    int woff = 0;
    for (int i = 0; i < w; ++i) woff += ws[i];
    int p = bsum[blockIdx.x] + woff + incl - lsum;  // exclusive base
#pragma unroll
    for (int k = 0; k < 4; ++k) {
        int idx = base + k;
        if (idx <= n) row_start[idx] = p;
        if (idx < n)  pos[idx] = p;
        p += v[k];
    }
}

__global__ __launch_bounds__(256) void fill_kernel(
    const int* __restrict__ src, const int* __restrict__ dst,
    int* __restrict__ pos, int* __restrict__ ssrc, int nE)
{
    int e = blockIdx.x * 256 + threadIdx.x;
    if (e < nE) {
        int p = atomicAdd(&pos[dst[e]], 1);
        ssrc[p] = src[e];
    }
}

// ---------------------------------------------------------------------------
// Gather-sum aggregation: agg[n] = sum_{e in CSR[n]} x[ssrc[e]].
// D/4 lanes per node, float4 per lane, register accumulation, no atomics.
// ---------------------------------------------------------------------------
template<int D>
__global__ __launch_bounds__(256) void gather_agg(
    const float* __restrict__ x, const int* __restrict__ row_start,
    const int* __restrict__ ssrc, float* __restrict__ agg, int nNodes)
{
    const int L = D / 4;        // lanes per node
    const int NPB = 256 / L;    // nodes per block
    int local = threadIdx.x / L;
    int lane  = threadIdx.x % L;
    int n = blockIdx.x * NPB + local;
    if (n >= nNodes) return;
    int beg = row_start[n], end = row_start[n + 1];
    float4 acc = make_float4(0.f, 0.f, 0.f, 0.f);
    int e = beg;
    for (; e + 1 < end; e += 2) {
        int s0 = ssrc[e], s1 = ssrc[e + 1];
        float4 v0 = *reinterpret_cast<const float4*>(x + (size_t)s0 * D + lane * 4);
        float4 v1 = *reinterpret_cast<const float4*>(x + (size_t)s1 * D + lane * 4);
        acc.x += v0.x; acc.y += v0.y; acc.z += v0.z; acc.w += v0.w;
        acc.x += v1.x; acc.y += v1.y; acc.z += v1.z; acc.w += v1.w;
    }
    if (e < end) {
        int s0 = ssrc[e];
        float4 v0 = *reinterpret_cast<const float4*>(x + (size_t)s0 * D + lane * 4);
        acc.x += v0.x; acc.y += v0.y; acc.z += v0.z; acc.w += v0.w;
    }
    *reinterpret_cast<float4*>(agg + (size_t)n * D + lane * 4) = acc;
}

// ---------------------------------------------------------------------------
// Node transform v3: inputs staged in LDS (padded pitch, bank-friendly),
// thread = (node, 8-output block), 8 VGPR accumulators, chunked k-loop.
// out[n][j0..j0+7] = ELU( agg[n]@w_rel + x[n]@w_root + b )[j0..j0+7]
// ---------------------------------------------------------------------------
template<int DIN, int DOUT>
__global__ __launch_bounds__(256) void transform_v3(
    const float* __restrict__ agg, const float* __restrict__ xin,
    const float* __restrict__ w_rel, const float* __restrict__ bias,
    const float* __restrict__ w_root, float* __restrict__ out, int nNodes)
{
    constexpr int JB = 8;               // outputs per thread
    constexpr int TPN = DOUT / JB;      // threads per node
    constexpr int NPB = 256 / TPN;      // nodes per block
    constexpr int PITCH = DIN + 4;      // 16B-aligned rows, spreads banks

    __shared__ float wr[DIN * DOUT];
    __shared__ float wt[DIN * DOUT];
    __shared__ float a_s[NPB * PITCH];
    __shared__ float x_s[NPB * PITCH];

    // weights -> LDS (vectorized, coalesced)
    {
        const float4* wr4 = reinterpret_cast<const float4*>(w_rel);
        const float4* wt4 = reinterpret_cast<const float4*>(w_root);
        float4* wrd = reinterpret_cast<float4*>(wr);
        float4* wtd = reinterpret_cast<float4*>(wt);
        for (int i = threadIdx.x; i < DIN * DOUT / 4; i += 256) {
            wrd[i] = wr4[i];
            wtd[i] = wt4[i];
        }
    }

    // input rows -> LDS (coalesced float4, padded rows)
    int n0 = blockIdx.x * NPB;
    constexpr int NV = NPB * DIN / 4;
    for (int v = threadIdx.x; v < NV; v += 256) {
        int row  = v / (DIN / 4);
        int col4 = v % (DIN / 4);
        int n = n0 + row;
        float4 a = make_float4(0.f, 0.f, 0.f, 0.f);
        float4 xx = a;
        if (n < nNodes) {
            a  = *reinterpret_cast<const float4*>(agg + (size_t)n * DIN + col4 * 4);
            xx = *reinterpret_cast<const float4*>(xin + (size_t)n * DIN + col4 * 4);
        }
        *reinterpret_cast<float4*>(&a_s[row * PITCH + col4 * 4]) = a;
        *reinterpret_cast<float4*>(&x_s[row * PITCH + col4 * 4]) = xx;
    }
    __syncthreads();

    int local = threadIdx.x / TPN;
    int j0 = (threadIdx.x % TPN) * JB;
    int n = n0 + local;

    float4 acc0 = *reinterpret_cast<const float4*>(bias + j0);
    float4 acc1 = *reinterpret_cast<const float4*>(bias + j0 + 4);

    const float* arow = &a_s[local * PITCH];
    const float* xrow = &x_s[local * PITCH];

    for (int c = 0; c < DIN; c += 8) {
#pragma unroll
        for (int kk = 0; kk < 8; ++kk) {
            int k = c + kk;
            float av = arow[k];
            float xv = xrow[k];
            float4 w0 = *reinterpret_cast<const float4*>(&wr[k * DOUT + j0]);
            float4 w1 = *reinterpret_cast<const float4*>(&wr[k * DOUT + j0 + 4]);
            float4 t0 = *reinterpret_cast<const float4*>(&wt[k * DOUT + j0]);
            float4 t1 = *reinterpret_cast<const float4*>(&wt[k * DOUT + j0 + 4]);
            acc0.x += av * w0.x + xv * t0.x;
            acc0.y += av * w0.y + xv * t0.y;
            acc0.z += av * w0.z + xv * t0.z;
            acc0.w += av * w0.w + xv * t0.w;
            acc1.x += av * w1.x + xv * t1.x;
            acc1.y += av * w1.y + xv * t1.y;
            acc1.z += av * w1.z + xv * t1.z;
            acc1.w += av * w1.w + xv * t1.w;
        }
    }

    if (n < nNodes) {
        float4 o0, o1;
        o0.x = elu_f(acc0.x); o0.y = elu_f(acc0.y); o0.z = elu_f(acc0.z); o0.w = elu_f(acc0.w);
        o1.x = elu_f(acc1.x); o1.y = elu_f(acc1.y); o1.z = elu_f(acc1.z); o1.w = elu_f(acc1.w);
        *reinterpret_cast<float4*>(out + (size_t)n * DOUT + j0)     = o0;
        *reinterpret_cast<float4*>(out + (size_t)n * DOUT + j0 + 4) = o1;
    }
}

// ---------------------------------------------------------------------------
// Mean-pool over sorted `batch`.
// ---------------------------------------------------------------------------
#define POOL_CHUNK 256
__global__ __launch_bounds__(64) void pool_kernel(
    const float* __restrict__ h, const int* __restrict__ batch,
    float* __restrict__ sums, float* __restrict__ cnts, int nNodes)
{
    int j = threadIdx.x;
    int start = blockIdx.x * POOL_CHUNK;
    int end = start + POOL_CHUNK;
    if (end > nNodes) end = nNodes;
    if (start >= end) return;

    int g = batch[start];
    float acc = 0.f;
    float c = 0.f;
    for (int n = start; n < end; ++n) {
        int gn = batch[n];
        if (gn != g) {
            unsafeAtomicAdd(&sums[(size_t)g * 64 + j], acc);
            if (j == 0) unsafeAtomicAdd(&cnts[g], c);
            acc = 0.f; c = 0.f; g = gn;
        }
        acc += h[(size_t)n * 64 + j];
        c += 1.f;
    }
    unsafeAtomicAdd(&sums[(size_t)g * 64 + j], acc);
    if (j == 0) unsafeAtomicAdd(&cnts[g], c);
}

// ---------------------------------------------------------------------------
// MLP head + log_softmax: one 64-thread block per graph.
// ---------------------------------------------------------------------------
__global__ __launch_bounds__(64) void mlp_kernel(
    const float* __restrict__ sums, const float* __restrict__ cnts,
    const float* __restrict__ fw1, const float* __restrict__ fb1,
    const float* __restrict__ fw2, const float* __restrict__ fb2,
    const float* __restrict__ fw3, const float* __restrict__ fb3,
    float* __restrict__ out)
{
    int g = blockIdx.x;
    int j = threadIdx.x;
    __shared__ float p[64];
    __shared__ float z1[64];
    __shared__ float z2[32];
    __shared__ float z3[10];
    __shared__ float lse;

    float c = fmaxf(cnts[g], 1.f);
    p[j] = sums[(size_t)g * 64 + j] / c;
    __syncthreads();

    float a = fb1[j];
#pragma unroll
    for (int k = 0; k < 64; ++k) a += p[k] * fw1[k * 64 + j];
    z1[j] = elu_f(a);
    __syncthreads();

    if (j < 32) {
        float a2 = fb2[j];
#pragma unroll
        for (int k = 0; k < 64; ++k) a2 += z1[k] * fw2[k * 32 + j];
        z2[j] = elu_f(a2);
    }
    __syncthreads();

    if (j < 10) {
        float a3 = fb3[j];
#pragma unroll
        for (int k = 0; k < 32; ++k) a3 += z2[k] * fw3[k * 10 + j];
        z3[j] = a3;
    }
    __syncthreads();

    if (j == 0) {
        float m = -1e30f;
        for (int i = 0; i < 10; ++i) m = fmaxf(m, z3[i]);
        float s = 0.f;
        for (int i = 0; i < 10; ++i) s += expf(z3[i] - m);
        lse = logf(s) + m;
    }
    __syncthreads();

    if (j < 10) out[(size_t)g * 10 + j] = z3[j] - lse;
}

// ---------------------------------------------------------------------------
extern "C" void kernel_launch(void* const* d_in, const int* in_sizes, int n_in,
                              void* d_out, int out_size, void* d_ws, size_t ws_size,
                              hipStream_t stream)
{
    const float* x       = (const float*)d_in[0];
    const int*   ei      = (const int*)  d_in[1];
    const int*   batch   = (const int*)  d_in[2];
    const float* w1_rel  = (const float*)d_in[3];
    const float* b1      = (const float*)d_in[4];
    const float* w1_root = (const float*)d_in[5];
    const float* w2_rel  = (const float*)d_in[6];
    const float* b2      = (const float*)d_in[7];
    const float* w2_root = (const float*)d_in[8];
    const float* w3_rel  = (const float*)d_in[9];
    const float* b3      = (const float*)d_in[10];
    const float* w3_root = (const float*)d_in[11];
    const float* fw1     = (const float*)d_in[12];
    const float* fb1     = (const float*)d_in[13];
    const float* fw2     = (const float*)d_in[14];
    const float* fb2     = (const float*)d_in[15];
    const float* fw3     = (const float*)d_in[16];
    const float* fb3     = (const float*)d_in[17];
    float* out = (float*)d_out;

    const int* src = ei;
    const int* dst = ei + N_EDGES_C;

    // workspace layout
    float* agg  = (float*)d_ws;                          // N*64 f
    float* hB   = agg  + (size_t)N_NODES_C * 64;         // N*64 f
    float* hC   = hB   + (size_t)N_NODES_C * 64;         // N*64 f
    float* sums = hC   + (size_t)N_NODES_C * 64;         // 512*64 f
    float* cnts = sums + (size_t)N_GRAPHS_C * 64;        // 512 f
    int*   deg  = (int*)(cnts + N_GRAPHS_C);             // N int
    int*   row_start = deg + N_NODES_C;                  // N+1 int
    int*   pos  = row_start + N_NODES_C + 1;             // N int
    int*   bsum = pos + N_NODES_C;                       // SCAN_NB int
    int*   ssrc = bsum + SCAN_NB;                        // nE int

    const int nb = (N_NODES_C + SCAN_CHUNK - 1) / SCAN_CHUNK;  // 98

    // ---- CSR build (once, reused by all 3 layers) ----
    hipMemsetAsync(deg, 0, (size_t)N_NODES_C * sizeof(int), stream);
    hist_kernel<<<(N_EDGES_C + 255) / 256, 256, 0, stream>>>(dst, deg, N_EDGES_C);
    scan_pass1<<<nb, 256, 0, stream>>>(deg, bsum, N_NODES_C);
    scan_pass2<<<1, 128, 0, stream>>>(bsum, nb);
    scan_pass3<<<nb, 256, 0, stream>>>(deg, bsum, row_start, pos, N_NODES_C);
    fill_kernel<<<(N_EDGES_C + 255) / 256, 256, 0, stream>>>(src, dst, pos, ssrc, N_EDGES_C);

    // ---- layer 1: 32 -> 32, input x, output hB ----
    // transform_v3<32,32>: TPN=4, NPB=64
    gather_agg<32><<<(N_NODES_C + 31) / 32, 256, 0, stream>>>(x, row_start, ssrc, agg, N_NODES_C);
    transform_v3<32, 32><<<(N_NODES_C + 63) / 64, 256, 0, stream>>>(
        agg, x, w1_rel, b1, w1_root, hB, N_NODES_C);

    // ---- layer 2: 32 -> 64, input hB, output hC ----
    // transform_v3<32,64>: TPN=8, NPB=32
    gather_agg<32><<<(N_NODES_C + 31) / 32, 256, 0, stream>>>(hB, row_start, ssrc, agg, N_NODES_C);
    transform_v3<32, 64><<<(N_NODES_C + 31) / 32, 256, 0, stream>>>(
        agg, hB, w2_rel, b2, w2_root, hC, N_NODES_C);

    // ---- layer 3: 64 -> 64, input hC, output hB ----
    // transform_v3<64,64>: TPN=8, NPB=32
    gather_agg<64><<<(N_NODES_C + 15) / 16, 256, 0, stream>>>(hC, row_start, ssrc, agg, N_NODES_C);
    transform_v3<64, 64><<<(N_NODES_C + 31) / 32, 256, 0, stream>>>(
        agg, hC, w3_rel, b3, w3_root, hB, N_NODES_C);

    // ---- mean pool ----
    hipMemsetAsync(sums, 0, ((size_t)N_GRAPHS_C * 64 + N_GRAPHS_C) * sizeof(float), stream);
    pool_kernel<<<(N_NODES_C + POOL_CHUNK - 1) / POOL_CHUNK, 64, 0, stream>>>(
        hB, batch, sums, cnts, N_NODES_C);

    // ---- MLP head + log_softmax ----
    mlp_kernel<<<N_GRAPHS_C, 64, 0, stream>>>(
        sums, cnts, fw1, fb1, fw2, fb2, fw3, fb3, out);
}

// Round 5
// 486.315 us; speedup vs baseline: 1.9389x; 1.5023x over previous
//
#include <hip/hip_runtime.h>
#include <hip/hip_bf16.h>
#include <math.h>

#define N_NODES_C 100000
#define N_EDGES_C 1600000
#define N_GRAPHS_C 512
#define SCAN_CHUNK 1024   // elements per scan block
#define SCAN_NB ((N_NODES_C + SCAN_CHUNK) / SCAN_CHUNK + 1)  // generous

__device__ __forceinline__ float elu_f(float x) { return x > 0.f ? x : expm1f(x); }

__device__ __forceinline__ int wave_incl_scan(int v) {
    int lane = threadIdx.x & 63;
#pragma unroll
    for (int o = 1; o < 64; o <<= 1) {
        int t = __shfl_up(v, o);
        if (lane >= o) v += t;
    }
    return v;
}

__device__ __forceinline__ int wave_sum_i(int v) {
#pragma unroll
    for (int o = 32; o > 0; o >>= 1) v += __shfl_xor(v, o);
    return v;
}

// ---------------------------------------------------------------------------
// CSR build: histogram of in-degrees, exclusive scan, positioned fill.
// ---------------------------------------------------------------------------
__global__ __launch_bounds__(256) void hist_kernel(
    const int* __restrict__ dst, int* __restrict__ deg, int nE)
{
    int e = blockIdx.x * 256 + threadIdx.x;
    if (e < nE) atomicAdd(&deg[dst[e]], 1);
}

__global__ __launch_bounds__(256) void scan_pass1(
    const int* __restrict__ deg, int* __restrict__ bsum, int n)
{
    int base = blockIdx.x * SCAN_CHUNK;
    int s = 0;
    for (int i = threadIdx.x; i < SCAN_CHUNK; i += 256) {
        int idx = base + i;
        if (idx < n) s += deg[idx];
    }
    s = wave_sum_i(s);
    __shared__ int ws[4];
    int lane = threadIdx.x & 63, w = threadIdx.x >> 6;
    if (lane == 0) ws[w] = s;
    __syncthreads();
    if (threadIdx.x == 0) bsum[blockIdx.x] = ws[0] + ws[1] + ws[2] + ws[3];
}

__global__ __launch_bounds__(128) void scan_pass2(int* __restrict__ bsum, int nb)
{
    int tid = threadIdx.x;  // 128 threads, nb <= 128
    int v = tid < nb ? bsum[tid] : 0;
    int lane = tid & 63, w = tid >> 6;
    int incl = wave_incl_scan(v);
    __shared__ int ws[2];
    if (lane == 63) ws[w] = incl;
    __syncthreads();
    int off = (w == 1) ? ws[0] : 0;
    if (tid < nb) bsum[tid] = off + incl - v;  // exclusive
}

__global__ __launch_bounds__(256) void scan_pass3(
    const int* __restrict__ deg, const int* __restrict__ bsum,
    int* __restrict__ row_start, int* __restrict__ pos, int n)
{
    int base = blockIdx.x * SCAN_CHUNK + threadIdx.x * 4;
    int v[4];
#pragma unroll
    for (int k = 0; k < 4; ++k) {
        int idx = base + k;
        v[k] = (idx < n) ? deg[idx] : 0;
    }
    int lsum = v[0] + v[1] + v[2] + v[3];
    int incl = wave_incl_scan(lsum);
    __shared__ int ws[4];
    int lane = threadIdx.x & 63, w = threadIdx.x >> 6;
    if (lane == 63) ws[w] = incl;
    __syncthreads();
    int woff = 0;
    for (int i = 0; i < w; ++i) woff += ws[i];
    int p = bsum[blockIdx.x] + woff + incl - lsum;  // exclusive base
#pragma unroll
    for (int k = 0; k < 4; ++k) {
        int idx = base + k;
        if (idx <= n) row_start[idx] = p;
        if (idx < n)  pos[idx] = p;
        p += v[k];
    }
}

__global__ __launch_bounds__(256) void fill_kernel(
    const int* __restrict__ src, const int* __restrict__ dst,
    int* __restrict__ pos, int* __restrict__ ssrc, int nE)
{
    int e = blockIdx.x * 256 + threadIdx.x;
    if (e < nE) {
        int p = atomicAdd(&pos[dst[e]], 1);
        ssrc[p] = src[e];
    }
}

// ---------------------------------------------------------------------------
// Gather-sum aggregation: agg[n] = sum_{e in CSR[n]} x[ssrc[e]].
// D/4 lanes per node, float4 per lane, register accumulation, no atomics.
// ---------------------------------------------------------------------------
template<int D>
__global__ __launch_bounds__(256) void gather_agg(
    const float* __restrict__ x, const int* __restrict__ row_start,
    const int* __restrict__ ssrc, float* __restrict__ agg, int nNodes)
{
    const int L = D / 4;        // lanes per node
    const int NPB = 256 / L;    // nodes per block
    int local = threadIdx.x / L;
    int lane  = threadIdx.x % L;
    int n = blockIdx.x * NPB + local;
    if (n >= nNodes) return;
    int beg = row_start[n], end = row_start[n + 1];
    float4 acc = make_float4(0.f, 0.f, 0.f, 0.f);
    int e = beg;
    for (; e + 1 < end; e += 2) {
        int s0 = ssrc[e], s1 = ssrc[e + 1];
        float4 v0 = *reinterpret_cast<const float4*>(x + (size_t)s0 * D + lane * 4);
        float4 v1 = *reinterpret_cast<const float4*>(x + (size_t)s1 * D + lane * 4);
        acc.x += v0.x; acc.y += v0.y; acc.z += v0.z; acc.w += v0.w;
        acc.x += v1.x; acc.y += v1.y; acc.z += v1.z; acc.w += v1.w;
    }
    if (e < end) {
        int s0 = ssrc[e];
        float4 v0 = *reinterpret_cast<const float4*>(x + (size_t)s0 * D + lane * 4);
        acc.x += v0.x; acc.y += v0.y; acc.z += v0.z; acc.w += v0.w;
    }
    *reinterpret_cast<float4*>(agg + (size_t)n * D + lane * 4) = acc;
}

// ---------------------------------------------------------------------------
// Node transform v4: inputs staged in LDS; thread = (2 nodes, 8 outputs);
// k-loop kept ROLLED (#pragma unroll 2) to bound the live-register window —
// v2/v3 fully unrolled and spilled (VGPR=256, 264MB scratch writes).
// ---------------------------------------------------------------------------
template<int DIN, int DOUT>
__global__ __launch_bounds__(256) void transform_v4(
    const float* __restrict__ agg, const float* __restrict__ xin,
    const float* __restrict__ w_rel, const float* __restrict__ bias,
    const float* __restrict__ w_root, float* __restrict__ out, int nNodes)
{
    constexpr int JB = 8;               // outputs per thread
    constexpr int TPN = DOUT / JB;      // threads per node
    constexpr int SLOTS = 256 / TPN;    // node slots per block
    constexpr int NT = 2;               // nodes per thread
    constexpr int NPB = SLOTS * NT;     // nodes per block
    constexpr int PITCH = DIN + 4;      // 16B-aligned padded rows

    __shared__ float wr[DIN * DOUT];
    __shared__ float wt[DIN * DOUT];
    __shared__ float a_s[NPB * PITCH];
    __shared__ float x_s[NPB * PITCH];

    // weights -> LDS (vectorized, coalesced)
    {
        const float4* wr4 = reinterpret_cast<const float4*>(w_rel);
        const float4* wt4 = reinterpret_cast<const float4*>(w_root);
        float4* wrd = reinterpret_cast<float4*>(wr);
        float4* wtd = reinterpret_cast<float4*>(wt);
        for (int i = threadIdx.x; i < DIN * DOUT / 4; i += 256) {
            wrd[i] = wr4[i];
            wtd[i] = wt4[i];
        }
    }

    // input rows -> LDS (coalesced float4, padded rows)
    int n0 = blockIdx.x * NPB;
    constexpr int NV = NPB * DIN / 4;
    for (int v = threadIdx.x; v < NV; v += 256) {
        int row  = v / (DIN / 4);
        int col4 = v % (DIN / 4);
        int n = n0 + row;
        float4 a = make_float4(0.f, 0.f, 0.f, 0.f);
        float4 xx = a;
        if (n < nNodes) {
            a  = *reinterpret_cast<const float4*>(agg + (size_t)n * DIN + col4 * 4);
            xx = *reinterpret_cast<const float4*>(xin + (size_t)n * DIN + col4 * 4);
        }
        *reinterpret_cast<float4*>(&a_s[row * PITCH + col4 * 4]) = a;
        *reinterpret_cast<float4*>(&x_s[row * PITCH + col4 * 4]) = xx;
    }
    __syncthreads();

    int slot = threadIdx.x / TPN;            // node slot A; node B = slot+SLOTS
    int j0 = (threadIdx.x % TPN) * JB;

    float4 biasLo = *reinterpret_cast<const float4*>(bias + j0);
    float4 biasHi = *reinterpret_cast<const float4*>(bias + j0 + 4);
    float4 accA0 = biasLo, accA1 = biasHi;
    float4 accB0 = biasLo, accB1 = biasHi;

    const float* arA = &a_s[slot * PITCH];
    const float* xrA = &x_s[slot * PITCH];
    const float* arB = arA + SLOTS * PITCH;
    const float* xrB = xrA + SLOTS * PITCH;

#pragma unroll 2
    for (int k = 0; k < DIN; ++k) {
        float aA = arA[k], xA = xrA[k];
        float aB = arB[k], xB = xrB[k];
        float4 w0 = *reinterpret_cast<const float4*>(&wr[k * DOUT + j0]);
        float4 w1 = *reinterpret_cast<const float4*>(&wr[k * DOUT + j0 + 4]);
        float4 t0 = *reinterpret_cast<const float4*>(&wt[k * DOUT + j0]);
        float4 t1 = *reinterpret_cast<const float4*>(&wt[k * DOUT + j0 + 4]);
        accA0.x += aA * w0.x + xA * t0.x;
        accA0.y += aA * w0.y + xA * t0.y;
        accA0.z += aA * w0.z + xA * t0.z;
        accA0.w += aA * w0.w + xA * t0.w;
        accA1.x += aA * w1.x + xA * t1.x;
        accA1.y += aA * w1.y + xA * t1.y;
        accA1.z += aA * w1.z + xA * t1.z;
        accA1.w += aA * w1.w + xA * t1.w;
        accB0.x += aB * w0.x + xB * t0.x;
        accB0.y += aB * w0.y + xB * t0.y;
        accB0.z += aB * w0.z + xB * t0.z;
        accB0.w += aB * w0.w + xB * t0.w;
        accB1.x += aB * w1.x + xB * t1.x;
        accB1.y += aB * w1.y + xB * t1.y;
        accB1.z += aB * w1.z + xB * t1.z;
        accB1.w += aB * w1.w + xB * t1.w;
    }

    int nA = n0 + slot;
    int nB = nA + SLOTS;
    if (nA < nNodes) {
        float4 o0, o1;
        o0.x = elu_f(accA0.x); o0.y = elu_f(accA0.y); o0.z = elu_f(accA0.z); o0.w = elu_f(accA0.w);
        o1.x = elu_f(accA1.x); o1.y = elu_f(accA1.y); o1.z = elu_f(accA1.z); o1.w = elu_f(accA1.w);
        *reinterpret_cast<float4*>(out + (size_t)nA * DOUT + j0)     = o0;
        *reinterpret_cast<float4*>(out + (size_t)nA * DOUT + j0 + 4) = o1;
    }
    if (nB < nNodes) {
        float4 o0, o1;
        o0.x = elu_f(accB0.x); o0.y = elu_f(accB0.y); o0.z = elu_f(accB0.z); o0.w = elu_f(accB0.w);
        o1.x = elu_f(accB1.x); o1.y = elu_f(accB1.y); o1.z = elu_f(accB1.z); o1.w = elu_f(accB1.w);
        *reinterpret_cast<float4*>(out + (size_t)nB * DOUT + j0)     = o0;
        *reinterpret_cast<float4*>(out + (size_t)nB * DOUT + j0 + 4) = o1;
    }
}

// ---------------------------------------------------------------------------
// Mean-pool over sorted `batch`.
// ---------------------------------------------------------------------------
#define POOL_CHUNK 256
__global__ __launch_bounds__(64) void pool_kernel(
    const float* __restrict__ h, const int* __restrict__ batch,
    float* __restrict__ sums, float* __restrict__ cnts, int nNodes)
{
    int j = threadIdx.x;
    int start = blockIdx.x * POOL_CHUNK;
    int end = start + POOL_CHUNK;
    if (end > nNodes) end = nNodes;
    if (start >= end) return;

    int g = batch[start];
    float acc = 0.f;
    float c = 0.f;
    for (int n = start; n < end; ++n) {
        int gn = batch[n];
        if (gn != g) {
            unsafeAtomicAdd(&sums[(size_t)g * 64 + j], acc);
            if (j == 0) unsafeAtomicAdd(&cnts[g], c);
            acc = 0.f; c = 0.f; g = gn;
        }
        acc += h[(size_t)n * 64 + j];
        c += 1.f;
    }
    unsafeAtomicAdd(&sums[(size_t)g * 64 + j], acc);
    if (j == 0) unsafeAtomicAdd(&cnts[g], c);
}

// ---------------------------------------------------------------------------
// MLP head + log_softmax: one 64-thread block per graph.
// ---------------------------------------------------------------------------
__global__ __launch_bounds__(64) void mlp_kernel(
    const float* __restrict__ sums, const float* __restrict__ cnts,
    const float* __restrict__ fw1, const float* __restrict__ fb1,
    const float* __restrict__ fw2, const float* __restrict__ fb2,
    const float* __restrict__ fw3, const float* __restrict__ fb3,
    float* __restrict__ out)
{
    int g = blockIdx.x;
    int j = threadIdx.x;
    __shared__ float p[64];
    __shared__ float z1[64];
    __shared__ float z2[32];
    __shared__ float z3[10];
    __shared__ float lse;

    float c = fmaxf(cnts[g], 1.f);
    p[j] = sums[(size_t)g * 64 + j] / c;
    __syncthreads();

    float a = fb1[j];
#pragma unroll
    for (int k = 0; k < 64; ++k) a += p[k] * fw1[k * 64 + j];
    z1[j] = elu_f(a);
    __syncthreads();

    if (j < 32) {
        float a2 = fb2[j];
#pragma unroll
        for (int k = 0; k < 64; ++k) a2 += z1[k] * fw2[k * 32 + j];
        z2[j] = elu_f(a2);
    }
    __syncthreads();

    if (j < 10) {
        float a3 = fb3[j];
#pragma unroll
        for (int k = 0; k < 32; ++k) a3 += z2[k] * fw3[k * 10 + j];
        z3[j] = a3;
    }
    __syncthreads();

    if (j == 0) {
        float m = -1e30f;
        for (int i = 0; i < 10; ++i) m = fmaxf(m, z3[i]);
        float s = 0.f;
        for (int i = 0; i < 10; ++i) s += expf(z3[i] - m);
        lse = logf(s) + m;
    }
    __syncthreads();

    if (j < 10) out[(size_t)g * 10 + j] = z3[j] - lse;
}

// ---------------------------------------------------------------------------
extern "C" void kernel_launch(void* const* d_in, const int* in_sizes, int n_in,
                              void* d_out, int out_size, void* d_ws, size_t ws_size,
                              hipStream_t stream)
{
    const float* x       = (const float*)d_in[0];
    const int*   ei      = (const int*)  d_in[1];
    const int*   batch   = (const int*)  d_in[2];
    const float* w1_rel  = (const float*)d_in[3];
    const float* b1      = (const float*)d_in[4];
    const float* w1_root = (const float*)d_in[5];
    const float* w2_rel  = (const float*)d_in[6];
    const float* b2      = (const float*)d_in[7];
    const float* w2_root = (const float*)d_in[8];
    const float* w3_rel  = (const float*)d_in[9];
    const float* b3      = (const float*)d_in[10];
    const float* w3_root = (const float*)d_in[11];
    const float* fw1     = (const float*)d_in[12];
    const float* fb1     = (const float*)d_in[13];
    const float* fw2     = (const float*)d_in[14];
    const float* fb2     = (const float*)d_in[15];
    const float* fw3     = (const float*)d_in[16];
    const float* fb3     = (const float*)d_in[17];
    float* out = (float*)d_out;

    const int* src = ei;
    const int* dst = ei + N_EDGES_C;

    // workspace layout
    float* agg  = (float*)d_ws;                          // N*64 f
    float* hB   = agg  + (size_t)N_NODES_C * 64;         // N*64 f
    float* hC   = hB   + (size_t)N_NODES_C * 64;         // N*64 f
    float* sums = hC   + (size_t)N_NODES_C * 64;         // 512*64 f
    float* cnts = sums + (size_t)N_GRAPHS_C * 64;        // 512 f
    int*   deg  = (int*)(cnts + N_GRAPHS_C);             // N int
    int*   row_start = deg + N_NODES_C;                  // N+1 int
    int*   pos  = row_start + N_NODES_C + 1;             // N int
    int*   bsum = pos + N_NODES_C;                       // SCAN_NB int
    int*   ssrc = bsum + SCAN_NB;                        // nE int

    const int nb = (N_NODES_C + SCAN_CHUNK - 1) / SCAN_CHUNK;  // 98

    // ---- CSR build (once, reused by all 3 layers) ----
    hipMemsetAsync(deg, 0, (size_t)N_NODES_C * sizeof(int), stream);
    hist_kernel<<<(N_EDGES_C + 255) / 256, 256, 0, stream>>>(dst, deg, N_EDGES_C);
    scan_pass1<<<nb, 256, 0, stream>>>(deg, bsum, N_NODES_C);
    scan_pass2<<<1, 128, 0, stream>>>(bsum, nb);
    scan_pass3<<<nb, 256, 0, stream>>>(deg, bsum, row_start, pos, N_NODES_C);
    fill_kernel<<<(N_EDGES_C + 255) / 256, 256, 0, stream>>>(src, dst, pos, ssrc, N_EDGES_C);

    // ---- layer 1: 32 -> 32, input x, output hB ----  (NPB=128)
    gather_agg<32><<<(N_NODES_C + 31) / 32, 256, 0, stream>>>(x, row_start, ssrc, agg, N_NODES_C);
    transform_v4<32, 32><<<(N_NODES_C + 127) / 128, 256, 0, stream>>>(
        agg, x, w1_rel, b1, w1_root, hB, N_NODES_C);

    // ---- layer 2: 32 -> 64, input hB, output hC ----  (NPB=64)
    gather_agg<32><<<(N_NODES_C + 31) / 32, 256, 0, stream>>>(hB, row_start, ssrc, agg, N_NODES_C);
    transform_v4<32, 64><<<(N_NODES_C + 63) / 64, 256, 0, stream>>>(
        agg, hB, w2_rel, b2, w2_root, hC, N_NODES_C);

    // ---- layer 3: 64 -> 64, input hC, output hB ----  (NPB=64)
    gather_agg<64><<<(N_NODES_C + 15) / 16, 256, 0, stream>>>(hC, row_start, ssrc, agg, N_NODES_C);
    transform_v4<64, 64><<<(N_NODES_C + 63) / 64, 256, 0, stream>>>(
        agg, hC, w3_rel, b3, w3_root, hB, N_NODES_C);

    // ---- mean pool ----
    hipMemsetAsync(sums, 0, ((size_t)N_GRAPHS_C * 64 + N_GRAPHS_C) * sizeof(float), stream);
    pool_kernel<<<(N_NODES_C + POOL_CHUNK - 1) / POOL_CHUNK, 64, 0, stream>>>(
        hB, batch, sums, cnts, N_NODES_C);

    // ---- MLP head + log_softmax ----
    mlp_kernel<<<N_GRAPHS_C, 64, 0, stream>>>(
        sums, cnts, fw1, fb1, fw2, fb2, fw3, fb3, out);
}